// Round 1
// baseline (806.590 us; speedup 1.0000x reference)
//
#include <hip/hip_runtime.h>
#include <math.h>

#define BATCH 64
#define TIME 400
#define BT (BATCH * TIME)   // 25600
#define S 25                // states
#define CH 80               // channels
#define CD (CH * CH)        // 6400

#define BT_TILE 32
#define CD_TILE 512
#define NTHREADS 256

// scale[k] = softplus(alpha_scaling[k]), numerically stable
__global__ void scale_kernel(const float* __restrict__ alpha_scaling,
                             float* __restrict__ scale) {
    int k = threadIdx.x;
    if (k < S) {
        float x = alpha_scaling[k];
        scale[k] = fmaxf(x, 0.0f) + log1pf(expf(-fabsf(x)));
    }
}

// m_t[bt][c] = sum_k alpha[bt][k] * scale[k] * mu[k][c]
// one float4 of output per thread; mu (8 KB) staged in LDS
__global__ __launch_bounds__(NTHREADS) void m_kernel(
    const float* __restrict__ alpha, const float* __restrict__ mu,
    const float* __restrict__ scale, float* __restrict__ out_m) {
    __shared__ float s_mu[S * CH];
    __shared__ float s_scale[S];
    for (int i = threadIdx.x; i < S * CH; i += NTHREADS) s_mu[i] = mu[i];
    if (threadIdx.x < S) s_scale[threadIdx.x] = scale[threadIdx.x];
    __syncthreads();

    int i4 = blockIdx.x * NTHREADS + threadIdx.x;  // float4 index
    const int total4 = BT * CH / 4;
    if (i4 >= total4) return;
    int e = i4 * 4;
    int bt = e / CH;            // CH=80 divisible by 4 -> float4 never crosses a row
    int c = e - bt * CH;
    const float* arow = alpha + (size_t)bt * S;
    float4 acc = {0.f, 0.f, 0.f, 0.f};
#pragma unroll
    for (int k = 0; k < S; k++) {
        float a = arow[k] * s_scale[k];
        float4 m4 = *(const float4*)&s_mu[k * CH + c];
        acc.x += a * m4.x;
        acc.y += a * m4.y;
        acc.z += a * m4.z;
        acc.w += a * m4.w;
    }
    *(float4*)&out_m[e] = acc;
}

// C_t[bt][cd] = sum_k alpha[bt][k]*scale[k] * D[k][cd]
// Tiled GEMM: [BT_TILE x S] * [S x CD_TILE], D chunk + scaled-a in LDS.
__global__ __launch_bounds__(NTHREADS) void c_kernel(
    const float* __restrict__ alpha, const float* __restrict__ D,
    const float* __restrict__ scale, float* __restrict__ out_c) {
    __shared__ float s_D[S * CD_TILE];   // 51.2 KB
    __shared__ float s_a[S * BT_TILE];   // 3.2 KB, layout [k][row] for b128 broadcast reads

    const int cd0 = blockIdx.x * CD_TILE;        // 13 tiles, last is partial (256 cols)
    const int bt0 = blockIdx.y * BT_TILE;        // 800 tiles
    const int vcols = min(CD_TILE, CD - cd0);
    const int tid = threadIdx.x;

    // stage scaled a: 800 contiguous floats from alpha
    for (int i = tid; i < S * BT_TILE; i += NTHREADS) {
        int row = i / S;
        int k = i - row * S;
        s_a[k * BT_TILE + row] = alpha[(size_t)(bt0 + row) * S + k] * scale[k];
    }
    // stage D chunk as float4 (coalesced within each k-row)
    const int nf4 = S * (CD_TILE / 4);  // 3200
    for (int i = tid; i < nf4; i += NTHREADS) {
        int k = i >> 7;            // / (CD_TILE/4) = 128
        int col = (i & 127) * 4;
        if (col < vcols) {
            float4 v = *(const float4*)&D[(size_t)k * CD + cd0 + col];
            *(float4*)&s_D[k * CD_TILE + col] = v;
        }
    }
    __syncthreads();

    const int c0 = 2 * tid;  // two adjacent columns per thread -> ds_read_b64
    float acc0[BT_TILE];
    float acc1[BT_TILE];
#pragma unroll
    for (int r = 0; r < BT_TILE; r++) {
        acc0[r] = 0.f;
        acc1[r] = 0.f;
    }

#pragma unroll 5
    for (int k = 0; k < S; k++) {
        float d0 = s_D[k * CD_TILE + c0];
        float d1 = s_D[k * CD_TILE + c0 + 1];
        const float4* a4 = (const float4*)&s_a[k * BT_TILE];
#pragma unroll
        for (int r4 = 0; r4 < BT_TILE / 4; r4++) {
            float4 av = a4[r4];  // broadcast b128 (same addr across wave)
            acc0[4 * r4 + 0] += av.x * d0;
            acc1[4 * r4 + 0] += av.x * d1;
            acc0[4 * r4 + 1] += av.y * d0;
            acc1[4 * r4 + 1] += av.y * d1;
            acc0[4 * r4 + 2] += av.z * d0;
            acc1[4 * r4 + 2] += av.z * d1;
            acc0[4 * r4 + 3] += av.w * d0;
            acc1[4 * r4 + 3] += av.w * d1;
        }
    }

    if (c0 < vcols) {
#pragma unroll
        for (int r = 0; r < BT_TILE; r++) {
            float2 v = {acc0[r], acc1[r]};
            *(float2*)&out_c[(size_t)(bt0 + r) * CD + cd0 + c0] = v;
        }
    }
}

extern "C" void kernel_launch(void* const* d_in, const int* in_sizes, int n_in,
                              void* d_out, int out_size, void* d_ws, size_t ws_size,
                              hipStream_t stream) {
    const float* alpha = (const float*)d_in[0];          // [64,400,25]
    const float* mu = (const float*)d_in[1];             // [25,80]
    const float* D = (const float*)d_in[2];              // [25,80,80]
    const float* alpha_scaling = (const float*)d_in[3];  // [25]

    float* out = (float*)d_out;
    float* out_m = out;               // [25600,80]
    float* out_c = out + BT * CH;     // [25600,6400]
    float* scale = (float*)d_ws;      // 25 floats

    scale_kernel<<<1, 64, 0, stream>>>(alpha_scaling, scale);

    const int total4 = BT * CH / 4;  // 512000
    m_kernel<<<(total4 + NTHREADS - 1) / NTHREADS, NTHREADS, 0, stream>>>(
        alpha, mu, scale, out_m);

    dim3 grid((CD + CD_TILE - 1) / CD_TILE, BT / BT_TILE);  // (13, 800)
    c_kernel<<<grid, NTHREADS, 0, stream>>>(alpha, D, scale, out_c);
}